// Round 1
// 1356.971 us; speedup vs baseline: 1.0709x; 1.0709x over previous
//
#include <hip/hip_runtime.h>
#include <stdint.h>

// Grouped GEMM (MoE experts): out[t,n] = sum_k x[t,k]*w[e(t),n,k] + bias[e(t),n]
// fp32 in/out, bf16 MFMA compute.
//
// v2: 256x256xBK64 tile, 512 threads (8 waves, 2M x 4N, per-wave 128x64 via
// 8x4 frags of mfma_f32_16x16x32_bf16). Single-barrier pipelined double
// buffer: per K-tile {pack+write landed tile} {issue next fp32 loads}
// BARRIER {MFMA}. 16B-granule XOR swizzle on LDS (conflict-free reads and
// writes). Bijective XCD-chunked grid swizzle, mt-major (4 nt-blocks sharing
// an X A-tile run consecutively on one XCD). Non-temporal C stores.

#define BM 256
#define BN 256
#define BK 64

typedef short v8s __attribute__((ext_vector_type(8)));
typedef float v4f __attribute__((ext_vector_type(4)));

static __device__ __forceinline__ uint32_t pk_bf16(float lo, float hi) {
    union { float f; uint32_t u; } a, b;
    a.f = lo; b.f = hi;
    // round-half-up to nearest bf16, pack two: dest = [lo.hi16, hi.hi16]
    return __builtin_amdgcn_perm(b.u + 0x8000u, a.u + 0x8000u, 0x07060302u);
}

__global__ __launch_bounds__(512, 2)
void Experts_Cute_54580444398293_kernel(const float* __restrict__ X,
                                        const float* __restrict__ W,
                                        const float* __restrict__ Bias,
                                        const int* __restrict__ counts,
                                        float* __restrict__ Out,
                                        int T, int E, int K, int N, int ntn) {
    // ---- bijective XCD-chunked swizzle (grid is multiple of 8 by construction)
    const int nb    = gridDim.x;
    const int chunk = nb >> 3;
    const int sw    = (blockIdx.x & 7) * chunk + (blockIdx.x >> 3);
    const int mt    = sw / ntn;        // M-tile (consecutive sw share mt -> X L2 reuse)
    const int nt    = sw - mt * ntn;   // N-tile

    // ---- resolve expert / row range for this M-tile (uniform scan) ----
    int e = -1, row0 = 0, rows = 0;
    {
        int tacc = 0, off = 0;
        for (int i = 0; i < E; ++i) {
            int c = counts[i];
            int ti = (c + BM - 1) / BM;
            if (mt < tacc + ti) {
                e = i;
                int local = mt - tacc;
                row0 = off + local * BM;
                rows = c - local * BM;
                if (rows > BM) rows = BM;
                break;
            }
            tacc += ti;
            off += c;
        }
    }
    if (e < 0) return;   // padding block (worst-case grid), uniform exit

    // 2 x (256x64 bf16) per operand = 128 KiB total, 1 block/CU
    __shared__ __align__(16) short As[2][BM * BK];
    __shared__ __align__(16) short Bs[2][BN * BK];

    const int tid = threadIdx.x;

    // staging: 16 lanes cover one row's 64 floats (256B contiguous); 32 rows/pass
    const int srow = tid >> 4;          // 0..31
    const int sc16 = tid & 15;
    const int scol4 = sc16 * 4;         // float col within BK

    // compute assignment: 8 waves as 2M x 4N
    const int lane = tid & 63;
    const int wv   = tid >> 6;          // 0..7
    const int wm   = (wv >> 2) * 128;   // 0 or 128
    const int wn   = (wv & 3) * 64;     // 0,64,128,192
    const int l16  = lane & 15;
    const int quad = lane >> 4;

    v4f acc[8][4];
#pragma unroll
    for (int i = 0; i < 8; ++i)
#pragma unroll
        for (int j = 0; j < 4; ++j)
            acc[i][j] = (v4f){0.f, 0.f, 0.f, 0.f};

    const float* Wtile = W + ((size_t)e * N + (size_t)nt * BN) * K;
    const int KT = K / BK;

    v4f ra[8], rb[8];   // in-flight fp32 stage registers (one K-tile)

    // ---- issue loads for K-tile 0 ----
#define ISSUE_LOADS(k0)                                                     \
    do {                                                                    \
        const float* Xp = X + (k0) + scol4;                                 \
        _Pragma("unroll")                                                   \
        for (int p = 0; p < 8; ++p) {                                       \
            int gr = row0 + p * 32 + srow;                                  \
            if (gr < T) ra[p] = *(const v4f*)(Xp + (size_t)gr * K);         \
            else        ra[p] = (v4f){0.f, 0.f, 0.f, 0.f};                  \
        }                                                                   \
        const float* Wp = Wtile + (k0) + scol4;                             \
        _Pragma("unroll")                                                   \
        for (int p = 0; p < 8; ++p)                                         \
            rb[p] = *(const v4f*)(Wp + (size_t)(p * 32 + srow) * K);        \
    } while (0)

    ISSUE_LOADS(0);
    int cur = 0;

    for (int kt = 0; kt < KT; ++kt) {
        // ---- pack + write the landed tile into buf[cur] (swizzled) ----
        // write addr: row*128B + ((byteCol>>4) ^ (row&7))*16 + (byteCol&15)
#pragma unroll
        for (int p = 0; p < 8; ++p) {
            int r = p * 32 + srow;
            uint32_t w0 = pk_bf16(ra[p].x, ra[p].y);
            uint32_t w1 = pk_bf16(ra[p].z, ra[p].w);
            int g = (sc16 >> 1) ^ (r & 7);
            *(uint2*)((char*)As[cur] + r * 128 + g * 16 + (sc16 & 1) * 8) =
                make_uint2(w0, w1);
        }
#pragma unroll
        for (int p = 0; p < 8; ++p) {
            int r = p * 32 + srow;
            uint32_t w0 = pk_bf16(rb[p].x, rb[p].y);
            uint32_t w1 = pk_bf16(rb[p].z, rb[p].w);
            int g = (sc16 >> 1) ^ (r & 7);
            *(uint2*)((char*)Bs[cur] + r * 128 + g * 16 + (sc16 & 1) * 8) =
                make_uint2(w0, w1);
        }

        // ---- issue global loads for next K-tile (land during MFMA phase) ----
        if (kt + 1 < KT) ISSUE_LOADS((kt + 1) * BK);

        __syncthreads();   // single barrier per K-tile (writes visible; prev reads done)

        // ---- MFMA on buf[cur]: 2 k-steps of 32 ----
        __builtin_amdgcn_s_setprio(1);
#pragma unroll
        for (int ks = 0; ks < 2; ++ks) {
            v8s bfr[4];
#pragma unroll
            for (int ni = 0; ni < 4; ++ni) {
                int r = wn + ni * 16 + l16;
                int g = ((ks * 4 + quad) ^ (r & 7));
                bfr[ni] = *(const v8s*)((char*)Bs[cur] + r * 128 + g * 16);
            }
#pragma unroll
            for (int mh = 0; mh < 2; ++mh) {
                v8s af[4];
#pragma unroll
                for (int i = 0; i < 4; ++i) {
                    int r = wm + (mh * 4 + i) * 16 + l16;
                    int g = ((ks * 4 + quad) ^ (r & 7));
                    af[i] = *(const v8s*)((char*)As[cur] + r * 128 + g * 16);
                }
#pragma unroll
                for (int i = 0; i < 4; ++i)
#pragma unroll
                    for (int ni = 0; ni < 4; ++ni)
                        acc[mh * 4 + i][ni] = __builtin_amdgcn_mfma_f32_16x16x32_bf16(
                            af[i], bfr[ni], acc[mh * 4 + i][ni], 0, 0, 0);
            }
        }
        __builtin_amdgcn_s_setprio(0);
        cur ^= 1;
    }
#undef ISSUE_LOADS

    // ---- epilogue: C/D layout col=lane&15, row=quad*4+reg; NT stores ----
#pragma unroll
    for (int ni = 0; ni < 4; ++ni) {
        const int col = nt * BN + wn + ni * 16 + l16;
        const float bv = Bias[(size_t)e * N + col];
#pragma unroll
        for (int mi = 0; mi < 8; ++mi) {
            const int rbase = wm + mi * 16 + quad * 4;
#pragma unroll
            for (int rr = 0; rr < 4; ++rr) {
                const int lr = rbase + rr;
                if (lr < rows)
                    __builtin_nontemporal_store(acc[mi][ni][rr] + bv,
                        &Out[(size_t)(row0 + lr) * N + col]);
            }
        }
    }
}

extern "C" void kernel_launch(void* const* d_in, const int* in_sizes, int n_in,
                              void* d_out, int out_size, void* d_ws, size_t ws_size,
                              hipStream_t stream) {
    const float* X      = (const float*)d_in[0];
    const int*   counts = (const int*)d_in[1];
    const float* W      = (const float*)d_in[2];
    const float* Bias   = (const float*)d_in[3];
    float* Out = (float*)d_out;

    const int E = in_sizes[1];
    const int N = in_sizes[3] / E;                 // D_OUT
    const int K = in_sizes[2] / in_sizes[3];       // D_IN
    const int T = in_sizes[0] / K;

    // worst-case M-tiles: sum_e ceil(c_e/BM) <= T/BM + E; pad to multiple of 8
    const int mtmax = (T + BM - 1) / BM + E;
    const int mt8   = (mtmax + 7) & ~7;
    const int ntn   = N / BN;
    const int nb    = ntn * mt8;                   // multiple of 8 (mt8 % 8 == 0)

    Experts_Cute_54580444398293_kernel<<<dim3(nb), 512, 0, stream>>>(
        X, W, Bias, counts, Out, T, E, K, N, ntn);
}